// Round 1
// baseline (1128.031 us; speedup 1.0000x reference)
//
#include <hip/hip_runtime.h>

constexpr int NN = 20000;   // nodes
constexpr int NE = 160000;  // edges  (= 625 * 256 exactly)

// ----------------------------------------------------------------------------
// ECC edge kernel: msg[e,o] = sum_{s,f} ehat[e,s] * h[src(e),f] * What[s,f,o]
// What rows 0..7 = We (layout s*(FI*FO) + f*FO + o), row 8 = be (f*FO + o).
// One thread per edge; What staged in LDS (broadcast reads are free);
// per-thread e-values staged in LDS stride-9 (conflict-free) so the s-loop
// can be a runtime loop (keeps code size inside I$).
// ----------------------------------------------------------------------------
template<int FI, int FO>
__global__ __launch_bounds__(256)
void ecc_edge_kernel(const float* __restrict__ h,
                     const int*  __restrict__ eidx,
                     const float* __restrict__ efeat,
                     const float* __restrict__ We,
                     const float* __restrict__ be,
                     float* __restrict__ agg)
{
    __shared__ float Wlds[9 * FI * FO];
    __shared__ float elds[256 * 9];
    const int tid = threadIdx.x;

    for (int i = tid; i < 9 * FI * FO; i += 256)
        Wlds[i] = (i < 8 * FI * FO) ? We[i] : be[i - 8 * FI * FO];

    const int eid = blockIdx.x * 256 + tid;   // NE == 625*256, no bounds check

    // e features -> LDS, slot 8 = 1.0 (bias channel)
    const float4* e4 = (const float4*)(efeat + (size_t)eid * 8);
    float4 ea = e4[0], eb = e4[1];
    float* ee = &elds[tid * 9];
    ee[0] = ea.x; ee[1] = ea.y; ee[2] = ea.z; ee[3] = ea.w;
    ee[4] = eb.x; ee[5] = eb.y; ee[6] = eb.z; ee[7] = eb.w;
    ee[8] = 1.0f;

    const int2 st = ((const int2*)eidx)[eid];
    const int src = st.x, tgt = st.y;

    float hv[FI];
    {
        const float4* h4 = (const float4*)(h + (size_t)src * FI);
        #pragma unroll
        for (int q = 0; q < FI / 4; q++) {
            float4 t = h4[q];
            hv[4*q+0] = t.x; hv[4*q+1] = t.y; hv[4*q+2] = t.z; hv[4*q+3] = t.w;
        }
    }

    float acc[FO];
    #pragma unroll
    for (int o = 0; o < FO; o++) acc[o] = 0.f;

    __syncthreads();

    #pragma unroll 1
    for (int s = 0; s < 9; s++) {
        const float us = ee[s];
        const float* wp = &Wlds[s * FI * FO];
        #pragma unroll
        for (int f = 0; f < FI; f++) {
            const float u = us * hv[f];
            #pragma unroll
            for (int o = 0; o < FO; o++)
                acc[o] = fmaf(u, wp[f * FO + o], acc[o]);
        }
    }

    float* ag = agg + (size_t)tgt * FO;
    #pragma unroll
    for (int o = 0; o < FO; o++)
        unsafeAtomicAdd(&ag[o], acc[o]);
}

// ----------------------------------------------------------------------------
// ECC node kernel: hout[n,o] = relu(agg[n,o] + sum_f h[n,f]*root[f,o] + b[o])
// ----------------------------------------------------------------------------
template<int FI, int FO>
__global__ __launch_bounds__(256)
void ecc_node_kernel(const float* __restrict__ h,
                     const float* __restrict__ agg,
                     const float* __restrict__ root,
                     const float* __restrict__ bias,
                     float* __restrict__ hout)
{
    __shared__ float Rlds[FI * FO];
    for (int i = threadIdx.x; i < FI * FO; i += 256) Rlds[i] = root[i];
    __syncthreads();

    const int n = blockIdx.x * 256 + threadIdx.x;
    if (n >= NN) return;

    float hv[FI];
    {
        const float4* h4 = (const float4*)(h + (size_t)n * FI);
        #pragma unroll
        for (int q = 0; q < FI / 4; q++) {
            float4 t = h4[q];
            hv[4*q+0] = t.x; hv[4*q+1] = t.y; hv[4*q+2] = t.z; hv[4*q+3] = t.w;
        }
    }

    float acc[FO];
    #pragma unroll
    for (int o = 0; o < FO; o++) acc[o] = bias[o];

    #pragma unroll
    for (int f = 0; f < FI; f++) {
        const float u = hv[f];
        #pragma unroll
        for (int o = 0; o < FO; o++)
            acc[o] = fmaf(u, Rlds[f * FO + o], acc[o]);
    }

    const float4* a4 = (const float4*)(agg + (size_t)n * FO);
    float4* out4 = (float4*)(hout + (size_t)n * FO);
    #pragma unroll
    for (int q = 0; q < FO / 4; q++) {
        float4 t = a4[q];
        float4 r;
        r.x = fmaxf(acc[4*q+0] + t.x, 0.f);
        r.y = fmaxf(acc[4*q+1] + t.y, 0.f);
        r.z = fmaxf(acc[4*q+2] + t.z, 0.f);
        r.w = fmaxf(acc[4*q+3] + t.w, 0.f);
        out4[q] = r;
    }
}

// ----------------------------------------------------------------------------
// Column sum over nodes: g[c] = sum_n h[n,c]   (h is N x 24; grid = 24 blocks)
// ----------------------------------------------------------------------------
__global__ __launch_bounds__(256)
void colsum_kernel(const float* __restrict__ h, float* __restrict__ g)
{
    const int c = blockIdx.x;
    float s = 0.f;
    for (int n = threadIdx.x; n < NN; n += 256)
        s += h[(size_t)n * 24 + c];
    __shared__ float red[256];
    red[threadIdx.x] = s;
    __syncthreads();
    for (int w = 128; w > 0; w >>= 1) {
        if (threadIdx.x < w) red[threadIdx.x] += red[threadIdx.x + w];
        __syncthreads();
    }
    if (threadIdx.x == 0) g[c] = red[0];
}

// ----------------------------------------------------------------------------
// Dense GEMV: y[o] = (relu?)(b[o] + sum_i x[i]*W[i,o])
// ----------------------------------------------------------------------------
template<bool RELU>
__global__ __launch_bounds__(256)
void gemv_kernel(const float* __restrict__ x, const float* __restrict__ W,
                 const float* __restrict__ b, float* __restrict__ y,
                 int fi, int fo)
{
    __shared__ float xs[768];
    for (int i = threadIdx.x; i < fi; i += 256) xs[i] = x[i];
    __syncthreads();
    const int o = blockIdx.x * 256 + threadIdx.x;
    if (o >= fo) return;
    float acc = b[o];
    for (int i = 0; i < fi; i++)
        acc = fmaf(xs[i], W[(size_t)i * fo + o], acc);
    y[o] = RELU ? fmaxf(acc, 0.f) : acc;
}

// ----------------------------------------------------------------------------
extern "C" void kernel_launch(void* const* d_in, const int* in_sizes, int n_in,
                              void* d_out, int out_size, void* d_ws, size_t ws_size,
                              hipStream_t stream)
{
    const float* x     = (const float*)d_in[0];
    const int*   eidx  = (const int*)  d_in[1];
    const float* e     = (const float*)d_in[2];
    const float* We1   = (const float*)d_in[3];
    const float* be1   = (const float*)d_in[4];
    const float* root1 = (const float*)d_in[5];
    const float* b1    = (const float*)d_in[6];
    const float* We2   = (const float*)d_in[7];
    const float* be2   = (const float*)d_in[8];
    const float* root2 = (const float*)d_in[9];
    const float* b2    = (const float*)d_in[10];
    const float* We3   = (const float*)d_in[11];
    const float* be3   = (const float*)d_in[12];
    const float* root3 = (const float*)d_in[13];
    const float* b3    = (const float*)d_in[14];
    const float* Wd1 = (const float*)d_in[15]; const float* bd1 = (const float*)d_in[16];
    const float* Wd2 = (const float*)d_in[17]; const float* bd2 = (const float*)d_in[18];
    const float* Wd3 = (const float*)d_in[19]; const float* bd3 = (const float*)d_in[20];
    const float* Wd4 = (const float*)d_in[21]; const float* bd4 = (const float*)d_in[22];
    const float* Wd5 = (const float*)d_in[23]; const float* bd5 = (const float*)d_in[24];
    const float* Wd6 = (const float*)d_in[25]; const float* bd6 = (const float*)d_in[26];

    float* ws = (float*)d_ws;
    float* agg1 = ws;                  // 20000*40 = 800000
    float* agg2 = agg1 + 800000;       // 20000*24 = 480000
    float* agg3 = agg2 + 480000;       // 480000   (aggs end at 1760000)
    float* h1   = agg3 + 480000;       // 800000
    float* h2   = h1   + 800000;       // 480000
    float* h3   = h2   + 480000;       // 480000
    float* g    = h3   + 480000;       // 24 (pad 32)
    float* m1   = g  + 32;             // 96
    float* m2   = m1 + 96;             // 256
    float* m3   = m2 + 256;            // 768
    float* m4   = m3 + 768;            // 512
    float* m5   = m4 + 512;            // 64

    // zero the three atomic-accumulated agg tables
    hipMemsetAsync(ws, 0, (size_t)1760000 * sizeof(float), stream);

    const int EB = NE / 256;            // 625
    const int NB = (NN + 255) / 256;    // 79

    // layer 1: fi=16 fo=40, h = x
    ecc_edge_kernel<16, 40><<<EB, 256, 0, stream>>>(x, eidx, e, We1, be1, agg1);
    ecc_node_kernel<16, 40><<<NB, 256, 0, stream>>>(x, agg1, root1, b1, h1);
    // layer 2: fi=40 fo=24
    ecc_edge_kernel<40, 24><<<EB, 256, 0, stream>>>(h1, eidx, e, We2, be2, agg2);
    ecc_node_kernel<40, 24><<<NB, 256, 0, stream>>>(h1, agg2, root2, b2, h2);
    // layer 3: fi=24 fo=24
    ecc_edge_kernel<24, 24><<<EB, 256, 0, stream>>>(h2, eidx, e, We3, be3, agg3);
    ecc_node_kernel<24, 24><<<NB, 256, 0, stream>>>(h2, agg3, root3, b3, h3);

    // readout
    colsum_kernel<<<24, 256, 0, stream>>>(h3, g);

    // MLP head: 24->96->256->768->512->64->1
    gemv_kernel<true ><<<1, 256, 0, stream>>>(g,  Wd1, bd1, m1, 24, 96);
    gemv_kernel<true ><<<1, 256, 0, stream>>>(m1, Wd2, bd2, m2, 96, 256);
    gemv_kernel<true ><<<3, 256, 0, stream>>>(m2, Wd3, bd3, m3, 256, 768);
    gemv_kernel<true ><<<2, 256, 0, stream>>>(m3, Wd4, bd4, m4, 768, 512);
    gemv_kernel<true ><<<1, 256, 0, stream>>>(m4, Wd5, bd5, m5, 512, 64);
    gemv_kernel<false><<<1, 256, 0, stream>>>(m5, Wd6, bd6, (float*)d_out, 64, 1);
}

// Round 2
// 536.545 us; speedup vs baseline: 2.1024x; 2.1024x over previous
//
#include <hip/hip_runtime.h>

constexpr int NN = 20000;   // nodes
constexpr int NE = 160000;  // edges  (= 625 * 256 exactly)

// ============================================================================
// CSR construction (by target). Built once per call, reused by all 3 layers.
// ============================================================================
__global__ __launch_bounds__(256)
void hist_kernel(const int* __restrict__ eidx, int* __restrict__ deg)
{
    const int eid = blockIdx.x * 256 + threadIdx.x;          // NE == 625*256
    const int tgt = ((const int2*)eidx)[eid].y;
    atomicAdd(&deg[tgt], 1);
}

// one block of 1024 threads; each thread owns 20 consecutive nodes
__global__ __launch_bounds__(1024)
void scan_kernel(const int* __restrict__ deg,
                 int* __restrict__ rowstart, int* __restrict__ cursor)
{
    const int tid = threadIdx.x;
    const int base = tid * 20;
    int s = 0;
    #pragma unroll
    for (int i = 0; i < 20; i++) {
        int idx = base + i;
        if (idx < NN) s += deg[idx];
    }
    __shared__ int tmp[1024];
    tmp[tid] = s;
    __syncthreads();
    for (int off = 1; off < 1024; off <<= 1) {
        int v = (tid >= off) ? tmp[tid - off] : 0;
        __syncthreads();
        tmp[tid] += v;
        __syncthreads();
    }
    int running = tmp[tid] - s;   // exclusive prefix of this thread's chunk
    #pragma unroll
    for (int i = 0; i < 20; i++) {
        int idx = base + i;
        if (idx < NN) {
            rowstart[idx] = running;
            cursor[idx]   = running;
            running += deg[idx];
        }
    }
}

__global__ __launch_bounds__(256)
void fill_kernel(const int* __restrict__ eidx, int* __restrict__ cursor,
                 int* __restrict__ adj)
{
    const int eid = blockIdx.x * 256 + threadIdx.x;
    const int tgt = ((const int2*)eidx)[eid].y;
    const int pos = atomicAdd(&cursor[tgt], 1);              // absolute slot
    adj[pos] = eid;
}

// ============================================================================
// Phase A: per-edge message compute, coalesced store to msg[eid*FOC + oc].
// msg[e,oc] = sum_{s,f} ehat[e,s] * h[src(e),f] * What[s,f,O0+oc]
// What rows 0..7 = We, row 8 = be (bias folded in as constant-1 channel).
// ============================================================================
template<int FI, int FO, int O0, int FOC>
__global__ __launch_bounds__(256)
void edge_msg_kernel(const float* __restrict__ h,
                     const int*  __restrict__ eidx,
                     const float* __restrict__ efeat,
                     const float* __restrict__ We,
                     const float* __restrict__ be,
                     float* __restrict__ msg)
{
    __shared__ float Wlds[9 * FI * FOC];
    __shared__ float elds[256 * 9];
    const int tid = threadIdx.x;

    for (int i = tid; i < 9 * FI * FOC; i += 256) {
        const int s  = i / (FI * FOC);
        const int r  = i % (FI * FOC);
        const int f  = r / FOC;
        const int oc = r % FOC;
        Wlds[i] = (s < 8) ? We[(size_t)s * FI * FO + f * FO + O0 + oc]
                          : be[f * FO + O0 + oc];
    }

    const int eid = blockIdx.x * 256 + tid;                  // NE == 625*256

    const float4* e4 = (const float4*)(efeat + (size_t)eid * 8);
    float4 ea = e4[0], eb = e4[1];
    float* ee = &elds[tid * 9];
    ee[0] = ea.x; ee[1] = ea.y; ee[2] = ea.z; ee[3] = ea.w;
    ee[4] = eb.x; ee[5] = eb.y; ee[6] = eb.z; ee[7] = eb.w;
    ee[8] = 1.0f;

    const int src = ((const int2*)eidx)[eid].x;

    float hv[FI];
    {
        const float4* h4 = (const float4*)(h + (size_t)src * FI);
        #pragma unroll
        for (int q = 0; q < FI / 4; q++) {
            float4 t = h4[q];
            hv[4*q+0] = t.x; hv[4*q+1] = t.y; hv[4*q+2] = t.z; hv[4*q+3] = t.w;
        }
    }

    float acc[FOC];
    #pragma unroll
    for (int o = 0; o < FOC; o++) acc[o] = 0.f;

    __syncthreads();

    #pragma unroll 1
    for (int s = 0; s < 9; s++) {
        const float us = ee[s];
        const float* wp = &Wlds[s * FI * FOC];
        #pragma unroll
        for (int f = 0; f < FI; f++) {
            const float u = us * hv[f];
            #pragma unroll
            for (int o = 0; o < FOC; o++)
                acc[o] = fmaf(u, wp[f * FOC + o], acc[o]);
        }
    }

    float4* m4 = (float4*)(msg + (size_t)eid * FOC);
    #pragma unroll
    for (int q = 0; q < FOC / 4; q++) {
        float4 t;
        t.x = acc[4*q+0]; t.y = acc[4*q+1]; t.z = acc[4*q+2]; t.w = acc[4*q+3];
        m4[q] = t;
    }
}

// ============================================================================
// Phase B: gather + root term + bias + relu.
// thread T -> (n = T/FOC, oc = T%FOC); o = O0+oc
// hout[n,o] = relu( sum_{j in edges->n} msg[adj[j]*FOC+oc]
//                   + sum_f h[n,f]*root[f,o] + b[o] )
// ============================================================================
template<int FI, int FO, int O0, int FOC>
__global__ __launch_bounds__(256)
void gather_kernel(const float* __restrict__ h,
                   const float* __restrict__ msg,
                   const int* __restrict__ rowstart,
                   const int* __restrict__ deg,
                   const int* __restrict__ adj,
                   const float* __restrict__ root,
                   const float* __restrict__ bias,
                   float* __restrict__ hout)
{
    __shared__ float Rlds[FI * FOC];
    for (int i = threadIdx.x; i < FI * FOC; i += 256) {
        const int f  = i / FOC;
        const int oc = i % FOC;
        Rlds[i] = root[f * FO + O0 + oc];
    }
    __syncthreads();

    const int T = blockIdx.x * 256 + threadIdx.x;
    if (T >= NN * FOC) return;
    const int n  = T / FOC;
    const int oc = T % FOC;

    float acc = bias[O0 + oc];

    // root term
    float hv[FI];
    {
        const float4* h4 = (const float4*)(h + (size_t)n * FI);
        #pragma unroll
        for (int q = 0; q < FI / 4; q++) {
            float4 t = h4[q];
            hv[4*q+0] = t.x; hv[4*q+1] = t.y; hv[4*q+2] = t.z; hv[4*q+3] = t.w;
        }
    }
    #pragma unroll
    for (int f = 0; f < FI; f++)
        acc = fmaf(hv[f], Rlds[f * FOC + oc], acc);

    // aggregation over incoming edges
    const int start = rowstart[n];
    const int d     = deg[n];
    for (int j = 0; j < d; j++) {
        const int eid = adj[start + j];
        acc += msg[(size_t)eid * FOC + oc];
    }

    hout[(size_t)n * FO + O0 + oc] = fmaxf(acc, 0.f);
}

// ============================================================================
// Column sum over nodes: g[c] = sum_n h[n,c]   (h is N x 24; grid = 24 blocks)
// ============================================================================
__global__ __launch_bounds__(256)
void colsum_kernel(const float* __restrict__ h, float* __restrict__ g)
{
    const int c = blockIdx.x;
    float s = 0.f;
    for (int n = threadIdx.x; n < NN; n += 256)
        s += h[(size_t)n * 24 + c];
    __shared__ float red[256];
    red[threadIdx.x] = s;
    __syncthreads();
    for (int w = 128; w > 0; w >>= 1) {
        if (threadIdx.x < w) red[threadIdx.x] += red[threadIdx.x + w];
        __syncthreads();
    }
    if (threadIdx.x == 0) g[c] = red[0];
}

// ============================================================================
// Dense GEMV: y[o] = (relu?)(b[o] + sum_i x[i]*W[i,o])
// ============================================================================
template<bool RELU>
__global__ __launch_bounds__(256)
void gemv_kernel(const float* __restrict__ x, const float* __restrict__ W,
                 const float* __restrict__ b, float* __restrict__ y,
                 int fi, int fo)
{
    __shared__ float xs[768];
    for (int i = threadIdx.x; i < fi; i += 256) xs[i] = x[i];
    __syncthreads();
    const int o = blockIdx.x * 256 + threadIdx.x;
    if (o >= fo) return;
    float acc = b[o];
    for (int i = 0; i < fi; i++)
        acc = fmaf(xs[i], W[(size_t)i * fo + o], acc);
    y[o] = RELU ? fmaxf(acc, 0.f) : acc;
}

// ============================================================================
extern "C" void kernel_launch(void* const* d_in, const int* in_sizes, int n_in,
                              void* d_out, int out_size, void* d_ws, size_t ws_size,
                              hipStream_t stream)
{
    const float* x     = (const float*)d_in[0];
    const int*   eidx  = (const int*)  d_in[1];
    const float* e     = (const float*)d_in[2];
    const float* We1   = (const float*)d_in[3];
    const float* be1   = (const float*)d_in[4];
    const float* root1 = (const float*)d_in[5];
    const float* b1    = (const float*)d_in[6];
    const float* We2   = (const float*)d_in[7];
    const float* be2   = (const float*)d_in[8];
    const float* root2 = (const float*)d_in[9];
    const float* b2    = (const float*)d_in[10];
    const float* We3   = (const float*)d_in[11];
    const float* be3   = (const float*)d_in[12];
    const float* root3 = (const float*)d_in[13];
    const float* b3    = (const float*)d_in[14];
    const float* Wd1 = (const float*)d_in[15]; const float* bd1 = (const float*)d_in[16];
    const float* Wd2 = (const float*)d_in[17]; const float* bd2 = (const float*)d_in[18];
    const float* Wd3 = (const float*)d_in[19]; const float* bd3 = (const float*)d_in[20];
    const float* Wd4 = (const float*)d_in[21]; const float* bd4 = (const float*)d_in[22];
    const float* Wd5 = (const float*)d_in[23]; const float* bd5 = (const float*)d_in[24];
    const float* Wd6 = (const float*)d_in[25]; const float* bd6 = (const float*)d_in[26];

    // ---- workspace layout ----
    int*   wi       = (int*)d_ws;
    int*   deg      = wi;                 // 20000
    int*   rowstart = wi + 20000;         // 20000
    int*   cursor   = wi + 40000;         // 20000
    int*   adj      = wi + 60000;         // 160000   (ints end at 220000)
    float* wf       = (float*)d_ws;
    float* msg      = wf + 220000;        // 160000*24 = 3,840,000 (max chunk)
    float* h1       = msg + 3840000;      // 20000*40 = 800000
    float* h2       = h1  + 800000;       // 480000
    float* h3       = h2  + 480000;       // 480000
    float* g        = h3  + 480000;       // 24 (pad 32)
    float* m1       = g  + 32;            // 96
    float* m2       = m1 + 96;            // 256
    float* m3       = m2 + 256;           // 768
    float* m4       = m3 + 768;           // 512
    float* m5       = m4 + 512;           // 64
    // total ~5.82M elems ~= 23.3 MB

    const int EB = NE / 256;              // 625

    // ---- CSR build (once; reused by all 3 layers) ----
    hipMemsetAsync(deg, 0, 20000 * sizeof(int), stream);
    hist_kernel<<<EB, 256, 0, stream>>>(eidx, deg);
    scan_kernel<<<1, 1024, 0, stream>>>(deg, rowstart, cursor);
    fill_kernel<<<EB, 256, 0, stream>>>(eidx, cursor, adj);

    // ---- layer 1: fi=16 fo=40, split into two 20-col chunks ----
    {
        const int GB = (NN * 20 + 255) / 256;   // 1563
        edge_msg_kernel<16, 40,  0, 20><<<EB, 256, 0, stream>>>(x, eidx, e, We1, be1, msg);
        gather_kernel  <16, 40,  0, 20><<<GB, 256, 0, stream>>>(x, msg, rowstart, deg, adj, root1, b1, h1);
        edge_msg_kernel<16, 40, 20, 20><<<EB, 256, 0, stream>>>(x, eidx, e, We1, be1, msg);
        gather_kernel  <16, 40, 20, 20><<<GB, 256, 0, stream>>>(x, msg, rowstart, deg, adj, root1, b1, h1);
    }
    // ---- layer 2: fi=40 fo=24 ----
    {
        const int GB = (NN * 24) / 256;         // 1875
        edge_msg_kernel<40, 24, 0, 24><<<EB, 256, 0, stream>>>(h1, eidx, e, We2, be2, msg);
        gather_kernel  <40, 24, 0, 24><<<GB, 256, 0, stream>>>(h1, msg, rowstart, deg, adj, root2, b2, h2);
    }
    // ---- layer 3: fi=24 fo=24 ----
    {
        const int GB = (NN * 24) / 256;         // 1875
        edge_msg_kernel<24, 24, 0, 24><<<EB, 256, 0, stream>>>(h2, eidx, e, We3, be3, msg);
        gather_kernel  <24, 24, 0, 24><<<GB, 256, 0, stream>>>(h2, msg, rowstart, deg, adj, root3, b3, h3);
    }

    // ---- readout ----
    colsum_kernel<<<24, 256, 0, stream>>>(h3, g);

    // ---- MLP head: 24->96->256->768->512->64->1 ----
    gemv_kernel<true ><<<1, 256, 0, stream>>>(g,  Wd1, bd1, m1, 24, 96);
    gemv_kernel<true ><<<1, 256, 0, stream>>>(m1, Wd2, bd2, m2, 96, 256);
    gemv_kernel<true ><<<3, 256, 0, stream>>>(m2, Wd3, bd3, m3, 256, 768);
    gemv_kernel<true ><<<2, 256, 0, stream>>>(m3, Wd4, bd4, m4, 768, 512);
    gemv_kernel<true ><<<1, 256, 0, stream>>>(m4, Wd5, bd5, m5, 512, 64);
    gemv_kernel<false><<<1, 256, 0, stream>>>(m5, Wd6, bd6, (float*)d_out, 64, 1);
}

// Round 3
// 379.014 us; speedup vs baseline: 2.9762x; 1.4156x over previous
//
#include <hip/hip_runtime.h>

constexpr int NN = 20000;   // nodes
constexpr int NE = 160000;  // edges  (= 625 * 256 exactly)

// ============================================================================
// CSR construction: tgt-CSR (for gather) + src-sorted permutation (for edge
// phase locality). Built once per call.
// ============================================================================
__global__ __launch_bounds__(256)
void hist_both_kernel(const int* __restrict__ eidx,
                      int* __restrict__ deg_t, int* __restrict__ deg_s)
{
    const int eid = blockIdx.x * 256 + threadIdx.x;          // NE == 625*256
    const int2 st = ((const int2*)eidx)[eid];
    atomicAdd(&deg_s[st.x], 1);
    atomicAdd(&deg_t[st.y], 1);
}

// 2 blocks of 1024 threads; block 0 scans deg_t, block 1 scans deg_s
__global__ __launch_bounds__(1024)
void scan_both_kernel(const int* __restrict__ deg_t, const int* __restrict__ deg_s,
                      int* __restrict__ rs_t, int* __restrict__ cur_t,
                      int* __restrict__ rs_s, int* __restrict__ cur_s)
{
    const int* deg = (blockIdx.x == 0) ? deg_t : deg_s;
    int* rs  = (blockIdx.x == 0) ? rs_t  : rs_s;
    int* cur = (blockIdx.x == 0) ? cur_t : cur_s;

    const int tid = threadIdx.x;
    const int base = tid * 20;
    int s = 0;
    #pragma unroll
    for (int i = 0; i < 20; i++) {
        int idx = base + i;
        if (idx < NN) s += deg[idx];
    }
    __shared__ int tmp[1024];
    tmp[tid] = s;
    __syncthreads();
    for (int off = 1; off < 1024; off <<= 1) {
        int v = (tid >= off) ? tmp[tid - off] : 0;
        __syncthreads();
        tmp[tid] += v;
        __syncthreads();
    }
    int running = tmp[tid] - s;
    #pragma unroll
    for (int i = 0; i < 20; i++) {
        int idx = base + i;
        if (idx < NN) {
            rs[idx]  = running;
            cur[idx] = running;
            running += deg[idx];
        }
    }
}

__global__ __launch_bounds__(256)
void fill_both_kernel(const int* __restrict__ eidx,
                      int* __restrict__ cur_t, int* __restrict__ cur_s,
                      int* __restrict__ adj,
                      int* __restrict__ eidorig, int* __restrict__ srcof)
{
    const int eid = blockIdx.x * 256 + threadIdx.x;
    const int2 st = ((const int2*)eidx)[eid];
    const int q = atomicAdd(&cur_t[st.y], 1);
    adj[q] = eid;
    const int p = atomicAdd(&cur_s[st.x], 1);
    eidorig[p] = eid;
    srcof[p]   = st.x;
}

// ============================================================================
// Node precompute: P[n, s*FOC+oc] = sum_f h[n,f] * We[s,f,O0+oc]  (s<8)
//                  P[n, 8*FOC+oc] = sum_f h[n,f] * be[f,O0+oc]    (bias chan)
// Dense GEMM [NN x FI] @ [FI x 9*FOC]; W staged in LDS, 64-node h tile in LDS.
// ============================================================================
template<int FI, int FO, int O0, int FOC>
__global__ __launch_bounds__(256)
void node_P_kernel(const float* __restrict__ h,
                   const float* __restrict__ We, const float* __restrict__ be,
                   float* __restrict__ P)
{
    constexpr int PW = 9 * FOC;          // P row width
    constexpr int C4 = PW / 4;
    __shared__ float Wlds[FI * PW];
    __shared__ float htile[64 * (FI + 1)];   // +1 pad: breaks 4-way bank alias
    const int tid = threadIdx.x;
    const int n0 = blockIdx.x * 64;

    for (int i = tid; i < FI * PW; i += 256) {
        const int f  = i / PW;
        const int c  = i % PW;
        const int s  = c / FOC;
        const int oc = c % FOC;
        Wlds[i] = (s < 8) ? We[(size_t)s * FI * FO + f * FO + O0 + oc]
                          : be[f * FO + O0 + oc];
    }
    for (int i = tid; i < 64 * FI; i += 256) {
        const int nl = i / FI, f = i % FI;
        const int n = n0 + nl;
        htile[nl * (FI + 1) + f] = (n < NN) ? h[(size_t)n * FI + f] : 0.f;
    }
    __syncthreads();

    const int nl = tid >> 2;             // 4 threads per node
    const int n  = n0 + nl;
    if (n >= NN) return;
    const float*  hr = &htile[nl * (FI + 1)];
    const float4* W4 = (const float4*)Wlds;
    float4* Pr = (float4*)(P + (size_t)n * PW);
    for (int cc = (tid & 3); cc < C4; cc += 4) {
        float4 a = {0.f, 0.f, 0.f, 0.f};
        #pragma unroll
        for (int f = 0; f < FI; f++) {
            const float  hf = hr[f];
            const float4 w  = W4[f * C4 + cc];
            a.x = fmaf(hf, w.x, a.x); a.y = fmaf(hf, w.y, a.y);
            a.z = fmaf(hf, w.z, a.z); a.w = fmaf(hf, w.w, a.w);
        }
        Pr[cc] = a;
    }
}

// ============================================================================
// Edge phase v2: iterate edges in src-sorted order p (consecutive threads
// share the same P row -> L1 broadcast). No LDS, full occupancy.
// msg[eid, oc] = P[src, 8*FOC+oc] + sum_{s<8} e[eid,s] * P[src, s*FOC+oc]
// ============================================================================
template<int FOC>
__global__ __launch_bounds__(256)
void edge_msg2_kernel(const int* __restrict__ eidorig,
                      const int* __restrict__ srcof,
                      const float* __restrict__ efeat,
                      const float* __restrict__ P,
                      float* __restrict__ msg)
{
    constexpr int C4 = FOC / 4;
    const int p = blockIdx.x * 256 + threadIdx.x;            // NE == 625*256
    const int eid = eidorig[p];
    const int src = srcof[p];

    const float4* e4 = (const float4*)(efeat + (size_t)eid * 8);
    const float4 ea = e4[0], eb = e4[1];
    const float es[8] = {ea.x, ea.y, ea.z, ea.w, eb.x, eb.y, eb.z, eb.w};

    const float4* Pr = (const float4*)(P + (size_t)src * (9 * FOC));

    float4 acc[C4];
    #pragma unroll
    for (int q = 0; q < C4; q++) acc[q] = Pr[8 * C4 + q];    // bias channel

    #pragma unroll
    for (int s = 0; s < 8; s++) {
        const float w = es[s];
        #pragma unroll
        for (int q = 0; q < C4; q++) {
            const float4 v = Pr[s * C4 + q];
            acc[q].x = fmaf(w, v.x, acc[q].x);
            acc[q].y = fmaf(w, v.y, acc[q].y);
            acc[q].z = fmaf(w, v.z, acc[q].z);
            acc[q].w = fmaf(w, v.w, acc[q].w);
        }
    }

    float4* m4 = (float4*)(msg + (size_t)eid * FOC);
    #pragma unroll
    for (int q = 0; q < C4; q++) m4[q] = acc[q];
}

// ============================================================================
// Gather + root term + bias + relu (unchanged from R2).
// ============================================================================
template<int FI, int FO, int O0, int FOC>
__global__ __launch_bounds__(256)
void gather_kernel(const float* __restrict__ h,
                   const float* __restrict__ msg,
                   const int* __restrict__ rowstart,
                   const int* __restrict__ deg,
                   const int* __restrict__ adj,
                   const float* __restrict__ root,
                   const float* __restrict__ bias,
                   float* __restrict__ hout)
{
    __shared__ float Rlds[FI * FOC];
    for (int i = threadIdx.x; i < FI * FOC; i += 256) {
        const int f  = i / FOC;
        const int oc = i % FOC;
        Rlds[i] = root[f * FO + O0 + oc];
    }
    __syncthreads();

    const int T = blockIdx.x * 256 + threadIdx.x;
    if (T >= NN * FOC) return;
    const int n  = T / FOC;
    const int oc = T % FOC;

    float acc = bias[O0 + oc];

    float hv[FI];
    {
        const float4* h4 = (const float4*)(h + (size_t)n * FI);
        #pragma unroll
        for (int q = 0; q < FI / 4; q++) {
            float4 t = h4[q];
            hv[4*q+0] = t.x; hv[4*q+1] = t.y; hv[4*q+2] = t.z; hv[4*q+3] = t.w;
        }
    }
    #pragma unroll
    for (int f = 0; f < FI; f++)
        acc = fmaf(hv[f], Rlds[f * FOC + oc], acc);

    const int start = rowstart[n];
    const int d     = deg[n];
    for (int j = 0; j < d; j++) {
        const int eid = adj[start + j];
        acc += msg[(size_t)eid * FOC + oc];
    }

    hout[(size_t)n * FO + O0 + oc] = fmaxf(acc, 0.f);
}

// ============================================================================
// Column sum: g[c] = sum_n h[n,c]. 24 cols x 8 node-slices = 192 blocks,
// one float atomic per block (g zeroed by the memset).
// ============================================================================
__global__ __launch_bounds__(256)
void colsum2_kernel(const float* __restrict__ h, float* __restrict__ g)
{
    const int c  = blockIdx.x % 24;
    const int sl = blockIdx.x / 24;          // 0..7, 2500 nodes each
    float s = 0.f;
    for (int n = sl * 2500 + threadIdx.x; n < (sl + 1) * 2500; n += 256)
        s += h[(size_t)n * 24 + c];
    __shared__ float red[256];
    red[threadIdx.x] = s;
    __syncthreads();
    for (int w = 128; w > 0; w >>= 1) {
        if (threadIdx.x < w) red[threadIdx.x] += red[threadIdx.x + w];
        __syncthreads();
    }
    if (threadIdx.x == 0) unsafeAtomicAdd(&g[c], red[0]);
}

// ============================================================================
// MLP GEMV v2: block = KG k-groups x OPB outputs (KG*OPB == 256), compile-time
// trip count, unrolled -> pipelined loads; LDS reduce; fused bias+relu.
// ============================================================================
template<int FI, int FO, int KG, int OPB, bool RELU>
__global__ __launch_bounds__(256)
void gemv2_kernel(const float* __restrict__ x, const float* __restrict__ W,
                  const float* __restrict__ b, float* __restrict__ y)
{
    static_assert(KG * OPB == 256 && FI % KG == 0, "cfg");
    __shared__ float xs[FI];
    __shared__ float red[256];
    for (int i = threadIdx.x; i < FI; i += 256) xs[i] = x[i];
    __syncthreads();

    const int kg = threadIdx.x / OPB;
    const int o  = threadIdx.x % OPB;
    const int og = blockIdx.x * OPB + o;
    constexpr int IT = FI / KG;

    float acc = 0.f;
    #pragma unroll 8
    for (int j = 0; j < IT; j++) {
        const int i = j * KG + kg;
        acc = fmaf(xs[i], W[(size_t)i * FO + og], acc);
    }
    red[threadIdx.x] = acc;
    __syncthreads();
    if (threadIdx.x < OPB) {
        float s = 0.f;
        #pragma unroll
        for (int k = 0; k < KG; k++) s += red[k * OPB + o];
        s += b[og];
        y[og] = RELU ? fmaxf(s, 0.f) : s;
    }
}

// final 64 -> 1 layer: one wave, shuffle reduce
__global__ __launch_bounds__(64)
void last1_kernel(const float* __restrict__ x, const float* __restrict__ W,
                  const float* __restrict__ b, float* __restrict__ y)
{
    float v = x[threadIdx.x] * W[threadIdx.x];
    #pragma unroll
    for (int off = 32; off > 0; off >>= 1)
        v += __shfl_down(v, off, 64);
    if (threadIdx.x == 0) y[0] = v + b[0];
}

// ============================================================================
extern "C" void kernel_launch(void* const* d_in, const int* in_sizes, int n_in,
                              void* d_out, int out_size, void* d_ws, size_t ws_size,
                              hipStream_t stream)
{
    const float* x     = (const float*)d_in[0];
    const int*   eidx  = (const int*)  d_in[1];
    const float* e     = (const float*)d_in[2];
    const float* We1   = (const float*)d_in[3];
    const float* be1   = (const float*)d_in[4];
    const float* root1 = (const float*)d_in[5];
    const float* b1    = (const float*)d_in[6];
    const float* We2   = (const float*)d_in[7];
    const float* be2   = (const float*)d_in[8];
    const float* root2 = (const float*)d_in[9];
    const float* b2    = (const float*)d_in[10];
    const float* We3   = (const float*)d_in[11];
    const float* be3   = (const float*)d_in[12];
    const float* root3 = (const float*)d_in[13];
    const float* b3    = (const float*)d_in[14];
    const float* Wd1 = (const float*)d_in[15]; const float* bd1 = (const float*)d_in[16];
    const float* Wd2 = (const float*)d_in[17]; const float* bd2 = (const float*)d_in[18];
    const float* Wd3 = (const float*)d_in[19]; const float* bd3 = (const float*)d_in[20];
    const float* Wd4 = (const float*)d_in[21]; const float* bd4 = (const float*)d_in[22];
    const float* Wd5 = (const float*)d_in[23]; const float* bd5 = (const float*)d_in[24];
    const float* Wd6 = (const float*)d_in[25]; const float* bd6 = (const float*)d_in[26];

    // ---- workspace layout (floats unless noted) ----
    int*   wi      = (int*)d_ws;
    int*   deg_t   = wi;                   //      0 .. 20000
    int*   deg_s   = wi + 20000;           //  20000 .. 40000
    float* g       = (float*)d_ws + 40000; //  40000 .. 40032  (zeroed w/ degs)
    int*   rs_t    = wi + 40032;
    int*   cur_t   = wi + 60032;
    int*   rs_s    = wi + 80032;
    int*   cur_s   = wi + 100032;
    int*   adj     = wi + 120032;          // 160000
    int*   eidorig = wi + 280032;          // 160000
    int*   srcof   = wi + 440032;          // 160000
    float* wf      = (float*)d_ws;
    float* P       = wf + 600032;          // max 20000*216 = 4,320,000
    float* msg     = P  + 4320000;         // max 160000*24 = 3,840,000
    float* h1      = msg + 3840000;        // 800000
    float* h2      = h1  + 800000;         // 480000
    float* h3      = h2  + 480000;         // 480000
    float* m1      = h3  + 480000;         // 96
    float* m2      = m1 + 96;              // 256
    float* m3      = m2 + 256;             // 768
    float* m4      = m3 + 768;             // 512
    float* m5      = m4 + 512;             // 64
    // total ~10.52M floats ~= 42.1 MB

    const int EB = NE / 256;               // 625
    const int PB = (NN + 63) / 64;         // 313

    // ---- CSR build: zero deg_t, deg_s, g in one memset ----
    hipMemsetAsync(d_ws, 0, (size_t)40032 * sizeof(float), stream);
    hist_both_kernel<<<EB, 256, 0, stream>>>(eidx, deg_t, deg_s);
    scan_both_kernel<<<2, 1024, 0, stream>>>(deg_t, deg_s, rs_t, cur_t, rs_s, cur_s);
    fill_both_kernel<<<EB, 256, 0, stream>>>(eidx, cur_t, cur_s, adj, eidorig, srcof);

    // ---- layer 1: fi=16 fo=40, two 20-col chunks ----
    {
        const int GB = (NN * 20 + 255) / 256;
        node_P_kernel <16, 40,  0, 20><<<PB, 256, 0, stream>>>(x, We1, be1, P);
        edge_msg2_kernel<20>          <<<EB, 256, 0, stream>>>(eidorig, srcof, e, P, msg);
        gather_kernel <16, 40,  0, 20><<<GB, 256, 0, stream>>>(x, msg, rs_t, deg_t, adj, root1, b1, h1);
        node_P_kernel <16, 40, 20, 20><<<PB, 256, 0, stream>>>(x, We1, be1, P);
        edge_msg2_kernel<20>          <<<EB, 256, 0, stream>>>(eidorig, srcof, e, P, msg);
        gather_kernel <16, 40, 20, 20><<<GB, 256, 0, stream>>>(x, msg, rs_t, deg_t, adj, root1, b1, h1);
    }
    // ---- layer 2: fi=40 fo=24 ----
    {
        const int GB = (NN * 24) / 256;
        node_P_kernel <40, 24, 0, 24><<<PB, 256, 0, stream>>>(h1, We2, be2, P);
        edge_msg2_kernel<24>         <<<EB, 256, 0, stream>>>(eidorig, srcof, e, P, msg);
        gather_kernel <40, 24, 0, 24><<<GB, 256, 0, stream>>>(h1, msg, rs_t, deg_t, adj, root2, b2, h2);
    }
    // ---- layer 3: fi=24 fo=24 ----
    {
        const int GB = (NN * 24) / 256;
        node_P_kernel <24, 24, 0, 24><<<PB, 256, 0, stream>>>(h2, We3, be3, P);
        edge_msg2_kernel<24>         <<<EB, 256, 0, stream>>>(eidorig, srcof, e, P, msg);
        gather_kernel <24, 24, 0, 24><<<GB, 256, 0, stream>>>(h2, msg, rs_t, deg_t, adj, root3, b3, h3);
    }

    // ---- readout ----
    colsum2_kernel<<<192, 256, 0, stream>>>(h3, g);

    // ---- MLP head: 24->96->256->768->512->64->1 ----
    gemv2_kernel< 24,  96, 8, 32, true ><<< 3, 256, 0, stream>>>(g,  Wd1, bd1, m1);
    gemv2_kernel< 96, 256, 8, 32, true ><<< 8, 256, 0, stream>>>(m1, Wd2, bd2, m2);
    gemv2_kernel<256, 768, 8, 32, true ><<<24, 256, 0, stream>>>(m2, Wd3, bd3, m3);
    gemv2_kernel<768, 512, 8, 32, true ><<<16, 256, 0, stream>>>(m3, Wd4, bd4, m4);
    gemv2_kernel<512,  64, 16, 16, true><<< 4, 256, 0, stream>>>(m4, Wd5, bd5, m5);
    last1_kernel<<<1, 64, 0, stream>>>(m5, Wd6, bd6, (float*)d_out);
}

// Round 4
// 343.202 us; speedup vs baseline: 3.2868x; 1.1043x over previous
//
#include <hip/hip_runtime.h>

constexpr int NN = 20000;   // nodes
constexpr int NE = 160000;  // edges  (= 625 * 256 exactly)

// ============================================================================
// CSR (by target) + e permuted into tgt order. Built once per call.
// ============================================================================
__global__ __launch_bounds__(256)
void hist_kernel(const int* __restrict__ eidx, int* __restrict__ deg)
{
    const int eid = blockIdx.x * 256 + threadIdx.x;          // NE == 625*256
    atomicAdd(&deg[((const int2*)eidx)[eid].y], 1);
}

// one block of 1024 threads; each thread owns 20 consecutive nodes
__global__ __launch_bounds__(1024)
void scan_kernel(const int* __restrict__ deg,
                 int* __restrict__ rowstart, int* __restrict__ cursor)
{
    const int tid = threadIdx.x;
    const int base = tid * 20;
    int s = 0;
    #pragma unroll
    for (int i = 0; i < 20; i++) {
        int idx = base + i;
        if (idx < NN) s += deg[idx];
    }
    __shared__ int tmp[1024];
    tmp[tid] = s;
    __syncthreads();
    for (int off = 1; off < 1024; off <<= 1) {
        int v = (tid >= off) ? tmp[tid - off] : 0;
        __syncthreads();
        tmp[tid] += v;
        __syncthreads();
    }
    int running = tmp[tid] - s;
    #pragma unroll
    for (int i = 0; i < 20; i++) {
        int idx = base + i;
        if (idx < NN) {
            rowstart[idx] = running;
            cursor[idx]   = running;
            running += deg[idx];
        }
    }
}

// scatter edges into tgt-sorted slots: adjsrc[q] = src, esort[q] = e[eid]
__global__ __launch_bounds__(256)
void fill_kernel(const int* __restrict__ eidx, const float* __restrict__ efeat,
                 int* __restrict__ cursor,
                 int* __restrict__ adjsrc, float* __restrict__ esort)
{
    const int eid = blockIdx.x * 256 + threadIdx.x;
    const int2 st = ((const int2*)eidx)[eid];
    const int q = atomicAdd(&cursor[st.y], 1);
    adjsrc[q] = st.x;
    const float4* e4 = (const float4*)(efeat + (size_t)eid * 8);
    float4* o4 = (float4*)(esort + (size_t)q * 8);
    o4[0] = e4[0];
    o4[1] = e4[1];
}

// ============================================================================
// Node precompute, width PW = 10*FO:
//   s in [0,8): P[n, s*FO+o] = sum_f h[n,f]*We[s,f,o]      (edge channels)
//   s == 8   : P[n, 8*FO+o] = sum_f h[n,f]*be[f,o]         (edge bias chan)
//   s == 9   : P[n, 9*FO+o] = sum_f h[n,f]*root[f,o] + b[o] (self/root term)
// Dense GEMM [NN x FI] @ [FI x PW]; W staged in LDS, 64-node h tile in LDS.
// ============================================================================
template<int FI, int FO>
__global__ __launch_bounds__(256)
void node_P_kernel(const float* __restrict__ h,
                   const float* __restrict__ We, const float* __restrict__ be,
                   const float* __restrict__ root, const float* __restrict__ bias,
                   float* __restrict__ P)
{
    constexpr int PW = 10 * FO;
    constexpr int C4 = PW / 4;           // float4 columns
    constexpr int F4 = FI / 4;
    __shared__ float Wlds[FI * PW];
    __shared__ float htile[64 * (FI + 4)];   // +4 pad keeps 16B align, breaks alias
    const int tid = threadIdx.x;
    const int n0 = blockIdx.x * 64;

    // stage W as float4 quads: Wlds[f*PW + s*FO + o]
    for (int t = tid; t < FI * C4; t += 256) {
        const int f  = t / C4;
        const int r  = t % C4;
        const int s  = r / (FO / 4);
        const int oq = r % (FO / 4);
        const float4* src;
        if (s < 8)       src = (const float4*)(We + (size_t)s * FI * FO + f * FO + oq * 4);
        else if (s == 8) src = (const float4*)(be + f * FO + oq * 4);
        else             src = (const float4*)(root + f * FO + oq * 4);
        ((float4*)Wlds)[t] = *src;
    }
    // stage 64-node h tile
    for (int t = tid; t < 64 * F4; t += 256) {
        const int nl = t / F4, fq = t % F4;
        const int n = n0 + nl;
        float4 v = {0.f, 0.f, 0.f, 0.f};
        if (n < NN) v = ((const float4*)(h + (size_t)n * FI))[fq];
        *((float4*)&htile[nl * (FI + 4) + fq * 4]) = v;
    }
    __syncthreads();

    const int nl = tid >> 2;             // 4 threads per node
    const int n  = n0 + nl;
    if (n >= NN) return;
    const float*  hr = &htile[nl * (FI + 4)];
    const float4* W4 = (const float4*)Wlds;
    float4* Pr = (float4*)(P + (size_t)n * PW);
    for (int cc = (tid & 3); cc < C4; cc += 4) {
        float4 a = {0.f, 0.f, 0.f, 0.f};
        #pragma unroll
        for (int f = 0; f < FI; f++) {
            const float  hf = hr[f];
            const float4 w  = W4[f * C4 + cc];
            a.x = fmaf(hf, w.x, a.x); a.y = fmaf(hf, w.y, a.y);
            a.z = fmaf(hf, w.z, a.z); a.w = fmaf(hf, w.w, a.w);
        }
        if (cc >= 9 * (FO / 4)) {        // root block: add bias
            const float4 b4 = ((const float4*)bias)[cc - 9 * (FO / 4)];
            a.x += b4.x; a.y += b4.y; a.z += b4.z; a.w += b4.w;
        }
        Pr[cc] = a;
    }
}

// ============================================================================
// Fused edge-compute + gather + relu. Thread (n,o):
// hout[n,o] = relu( P[n,9*FO+o]
//                 + sum_{q in in-edges(n)} [ P[src_q,8*FO+o]
//                     + sum_{s<8} esort[q,s]*P[src_q,s*FO+o] ] )
// ============================================================================
template<int FO>
__global__ __launch_bounds__(256)
void gather_fused_kernel(const float* __restrict__ P,
                         const int* __restrict__ rowstart,
                         const int* __restrict__ deg,
                         const int* __restrict__ adjsrc,
                         const float* __restrict__ esort,
                         float* __restrict__ hout)
{
    constexpr int PW = 10 * FO;
    const int T = blockIdx.x * 256 + threadIdx.x;
    if (T >= NN * FO) return;
    const int n = T / FO;
    const int o = T % FO;

    float acc = P[(size_t)n * PW + 9 * FO + o];   // root + bias term

    const int start = rowstart[n];
    const int d     = deg[n];
    for (int j = 0; j < d; j++) {
        const int q   = start + j;
        const int src = adjsrc[q];
        const float* Pr = P + (size_t)src * PW + o;
        const float* eq = esort + (size_t)q * 8;
        float a = Pr[8 * FO];                     // edge bias channel
        #pragma unroll
        for (int s = 0; s < 8; s++)
            a = fmaf(eq[s], Pr[s * FO], a);
        acc += a;
    }

    hout[T] = fmaxf(acc, 0.f);
}

// ============================================================================
// Column sum: g[c] = sum_n h[n,c]. 24 cols x 8 node-slices = 192 blocks,
// one float atomic per block (g zeroed by the memset).
// ============================================================================
__global__ __launch_bounds__(256)
void colsum2_kernel(const float* __restrict__ h, float* __restrict__ g)
{
    const int c  = blockIdx.x % 24;
    const int sl = blockIdx.x / 24;          // 0..7, 2500 nodes each
    float s = 0.f;
    for (int n = sl * 2500 + threadIdx.x; n < (sl + 1) * 2500; n += 256)
        s += h[(size_t)n * 24 + c];
    __shared__ float red[256];
    red[threadIdx.x] = s;
    __syncthreads();
    for (int w = 128; w > 0; w >>= 1) {
        if (threadIdx.x < w) red[threadIdx.x] += red[threadIdx.x + w];
        __syncthreads();
    }
    if (threadIdx.x == 0) unsafeAtomicAdd(&g[c], red[0]);
}

// ============================================================================
// MLP GEMV: block = KG k-groups x OPB outputs (KG*OPB == 256), compile-time
// trip count, unrolled -> pipelined loads; LDS reduce; fused bias+relu.
// ============================================================================
template<int FI, int FO, int KG, int OPB, bool RELU>
__global__ __launch_bounds__(256)
void gemv2_kernel(const float* __restrict__ x, const float* __restrict__ W,
                  const float* __restrict__ b, float* __restrict__ y)
{
    static_assert(KG * OPB == 256 && FI % KG == 0, "cfg");
    __shared__ float xs[FI];
    __shared__ float red[256];
    for (int i = threadIdx.x; i < FI; i += 256) xs[i] = x[i];
    __syncthreads();

    const int kg = threadIdx.x / OPB;
    const int o  = threadIdx.x % OPB;
    const int og = blockIdx.x * OPB + o;
    constexpr int IT = FI / KG;

    float acc = 0.f;
    #pragma unroll 8
    for (int j = 0; j < IT; j++) {
        const int i = j * KG + kg;
        acc = fmaf(xs[i], W[(size_t)i * FO + og], acc);
    }
    red[threadIdx.x] = acc;
    __syncthreads();
    if (threadIdx.x < OPB) {
        float s = 0.f;
        #pragma unroll
        for (int k = 0; k < KG; k++) s += red[k * OPB + o];
        s += b[og];
        y[og] = RELU ? fmaxf(s, 0.f) : s;
    }
}

// final 64 -> 1 layer: one wave, shuffle reduce
__global__ __launch_bounds__(64)
void last1_kernel(const float* __restrict__ x, const float* __restrict__ W,
                  const float* __restrict__ b, float* __restrict__ y)
{
    float v = x[threadIdx.x] * W[threadIdx.x];
    #pragma unroll
    for (int off = 32; off > 0; off >>= 1)
        v += __shfl_down(v, off, 64);
    if (threadIdx.x == 0) y[0] = v + b[0];
}

// ============================================================================
extern "C" void kernel_launch(void* const* d_in, const int* in_sizes, int n_in,
                              void* d_out, int out_size, void* d_ws, size_t ws_size,
                              hipStream_t stream)
{
    const float* x     = (const float*)d_in[0];
    const int*   eidx  = (const int*)  d_in[1];
    const float* e     = (const float*)d_in[2];
    const float* We1   = (const float*)d_in[3];
    const float* be1   = (const float*)d_in[4];
    const float* root1 = (const float*)d_in[5];
    const float* b1    = (const float*)d_in[6];
    const float* We2   = (const float*)d_in[7];
    const float* be2   = (const float*)d_in[8];
    const float* root2 = (const float*)d_in[9];
    const float* b2    = (const float*)d_in[10];
    const float* We3   = (const float*)d_in[11];
    const float* be3   = (const float*)d_in[12];
    const float* root3 = (const float*)d_in[13];
    const float* b3    = (const float*)d_in[14];
    const float* Wd1 = (const float*)d_in[15]; const float* bd1 = (const float*)d_in[16];
    const float* Wd2 = (const float*)d_in[17]; const float* bd2 = (const float*)d_in[18];
    const float* Wd3 = (const float*)d_in[19]; const float* bd3 = (const float*)d_in[20];
    const float* Wd4 = (const float*)d_in[21]; const float* bd4 = (const float*)d_in[22];
    const float* Wd5 = (const float*)d_in[23]; const float* bd5 = (const float*)d_in[24];
    const float* Wd6 = (const float*)d_in[25]; const float* bd6 = (const float*)d_in[26];

    // ---- workspace layout (4-byte units) ----
    int*   wi      = (int*)d_ws;
    int*   deg_t   = wi;                    //       0 ..   20000
    float* g       = (float*)d_ws + 20000;  //   20000 ..   20032 (zeroed w/ deg)
    int*   rs_t    = wi + 20032;            //   20032 ..   40032
    int*   cur_t   = wi + 40032;            //   40032 ..   60032
    int*   adjsrc  = wi + 60032;            //   60032 ..  220032
    float* wf      = (float*)d_ws;
    float* esort   = wf + 220032;           // 160000*8 = 1,280,000
    float* P       = wf + 1500032;          // max 20000*400 = 8,000,000
    float* h1      = P   + 8000000;         // 800000
    float* h2      = h1  + 800000;          // 480000
    float* h3      = h2  + 480000;          // 480000
    float* m1      = h3  + 480000;          // 96
    float* m2      = m1 + 96;               // 256
    float* m3      = m2 + 256;              // 768
    float* m4      = m3 + 768;              // 512
    float* m5      = m4 + 512;              // 64
    // total ~11.26M floats ~= 45 MB

    const int EB = NE / 256;                // 625
    const int PB = (NN + 63) / 64;          // 313

    // ---- CSR build (zero deg_t and g in one memset) ----
    hipMemsetAsync(d_ws, 0, (size_t)20032 * sizeof(float), stream);
    hist_kernel<<<EB, 256, 0, stream>>>(eidx, deg_t);
    scan_kernel<<<1, 1024, 0, stream>>>(deg_t, rs_t, cur_t);
    fill_kernel<<<EB, 256, 0, stream>>>(eidx, e, cur_t, adjsrc, esort);

    // ---- layer 1: fi=16 fo=40 ----
    node_P_kernel<16, 40><<<PB, 256, 0, stream>>>(x, We1, be1, root1, b1, P);
    gather_fused_kernel<40><<<(NN * 40 + 255) / 256, 256, 0, stream>>>(P, rs_t, deg_t, adjsrc, esort, h1);
    // ---- layer 2: fi=40 fo=24 ----
    node_P_kernel<40, 24><<<PB, 256, 0, stream>>>(h1, We2, be2, root2, b2, P);
    gather_fused_kernel<24><<<(NN * 24 + 255) / 256, 256, 0, stream>>>(P, rs_t, deg_t, adjsrc, esort, h2);
    // ---- layer 3: fi=24 fo=24 ----
    node_P_kernel<24, 24><<<PB, 256, 0, stream>>>(h2, We3, be3, root3, b3, P);
    gather_fused_kernel<24><<<(NN * 24 + 255) / 256, 256, 0, stream>>>(P, rs_t, deg_t, adjsrc, esort, h3);

    // ---- readout ----
    colsum2_kernel<<<192, 256, 0, stream>>>(h3, g);

    // ---- MLP head: 24->96->256->768->512->64->1 ----
    gemv2_kernel< 24,  96, 8, 32, true ><<< 3, 256, 0, stream>>>(g,  Wd1, bd1, m1);
    gemv2_kernel< 96, 256, 8, 32, true ><<< 8, 256, 0, stream>>>(m1, Wd2, bd2, m2);
    gemv2_kernel<256, 768, 8, 32, true ><<<24, 256, 0, stream>>>(m2, Wd3, bd3, m3);
    gemv2_kernel<768, 512, 8, 32, true ><<<16, 256, 0, stream>>>(m3, Wd4, bd4, m4);
    gemv2_kernel<512,  64, 16, 16, true><<< 4, 256, 0, stream>>>(m4, Wd5, bd5, m5);
    last1_kernel<<<1, 64, 0, stream>>>(m5, Wd6, bd6, (float*)d_out);
}